// Round 4
// baseline (354.092 us; speedup 1.0000x reference)
//
#include <hip/hip_runtime.h>
#include <stdint.h>

typedef short short8 __attribute__((ext_vector_type(8)));
typedef float f32x4 __attribute__((ext_vector_type(4)));
typedef unsigned short u16;
typedef unsigned int u32;

struct alignas(8) U16x4 { u16 x, y, z, w; };

__device__ __forceinline__ u16 f2bf(float f) {
  u32 u = __float_as_uint(f);
  u += 0x7fffu + ((u >> 16) & 1u);
  return (u16)(u >> 16);
}
__device__ __forceinline__ float bf2f(u16 v) {
  return __uint_as_float(((u32)v) << 16);
}

__device__ __forceinline__ void gld_lds16(const u16* g, u16* l) {
  __builtin_amdgcn_global_load_lds((const __attribute__((address_space(1))) u32*)g,
                                   (__attribute__((address_space(3))) u32*)l,
                                   16, 0, 0);
}

__device__ __forceinline__ void mfma16x16x32(f32x4& c, short8 a, short8 b) {
  asm("v_mfma_f32_16x16x32_bf16 %0, %1, %2, %0" : "+v"(c) : "v"(a), "v"(b));
}

// ---------------------------------------------------------------------------
// Batched C = A * B^T (A:[M,K] rm, Bt:[N,K] rm). 512 threads (8 waves, wave
// tile 32x64), BK=64, double-buffered LDS with COUNTED vmcnt pipeline:
//   barrier; stage(next: 4 gld_lds/wave); s_waitcnt vmcnt(4); barrier; MFMA
// Tile t's loads are issued one full iteration ahead; vmcnt(4) waits only for
// them (never drains the in-flight prefetch).
// EPI 0: bf16 out; EPI 6: bf16 + v1[b512+row]*v2[col] + v3[row]*v4[b512+col];
// EPI 4: f32 out, acc*v1[row] + v2[b512+row] + xres[b][row][col]
// ---------------------------------------------------------------------------
template<int EPI>
__global__ void __launch_bounds__(512, 4) gemm_abt(
                         const u16* __restrict__ A, int64_t Abs,
                         const u16* __restrict__ Bt, int64_t Bbs,
                         void* __restrict__ Cptr, int64_t Cbs,
                         int M, int N, int K,
                         const float* __restrict__ v1,
                         const float* __restrict__ v2,
                         const float* __restrict__ v3,
                         const float* __restrict__ v4,
                         const float* __restrict__ xres) {
  constexpr int BM = 128, BN = 128, BK = 64;
  __shared__ u16 As[2][BM * BK];
  __shared__ u16 Bs[2][BN * BK];

  const int b = blockIdx.z;
  const u16* Ab = A + (int64_t)b * Abs;
  const u16* Bb = Bt + (int64_t)b * Bbs;
  const int brow = blockIdx.y * BM, bcol = blockIdx.x * BN;
  const int tid = threadIdx.x, lane = tid & 63, w = tid >> 6;
  const int wr = w >> 1, wc = w & 1;  // 4x2 wave grid; wave tile 32 rows x 64 cols

  f32x4 acc[2][4] = {};

  // staging: thread t -> rows (t>>3) and (t>>3)+64, col chunk (t&7)*8.
  // LDS linear: wave-uniform base (w*1024B) + lane*16B per chunk. 4 gld/wave.
  const int sr = tid >> 3;
  const int sc = (tid & 7) * 8;
  u16* lA0 = &As[0][sr * BK + sc];
  u16* lB0 = &Bs[0][sr * BK + sc];
  const u16* gA = Ab + (int64_t)(brow + sr) * K + sc;
  const u16* gB = Bb + (int64_t)(bcol + sr) * K + sc;

  const int la16 = lane & 15;
  const int kg = (lane >> 4) * 8;
  const int nt = K / BK;

  // prologue: stage tile 0 into buf 0
  gld_lds16(gA, lA0);
  gld_lds16(gA + (int64_t)64 * K, lA0 + 64 * BK);
  gld_lds16(gB, lB0);
  gld_lds16(gB + (int64_t)64 * K, lB0 + 64 * BK);

  for (int t = 0; t < nt; ++t) {
    __builtin_amdgcn_s_barrier();  // prev iter's LDS reads done before overwrite
    if (t + 1 < nt) {
      const int nb = (t + 1) & 1;
      const int k0 = (t + 1) * BK;
      u16* la = lA0 + nb * BM * BK;
      u16* lb = lB0 + nb * BN * BK;
      gld_lds16(gA + k0, la);
      gld_lds16(gA + (int64_t)64 * K + k0, la + 64 * BK);
      gld_lds16(gB + k0, lb);
      gld_lds16(gB + (int64_t)64 * K + k0, lb + 64 * BK);
      asm volatile("s_waitcnt vmcnt(4)" ::: "memory");  // tile t landed; next stays in flight
    } else {
      asm volatile("s_waitcnt vmcnt(0)" ::: "memory");
    }
    __builtin_amdgcn_s_barrier();
    __builtin_amdgcn_sched_barrier(0);
    const u16* as = As[t & 1];
    const u16* bs = Bs[t & 1];
#pragma unroll
    for (int kk = 0; kk < 2; ++kk) {
      short8 af[2], bf[4];
#pragma unroll
      for (int m = 0; m < 2; ++m)
        af[m] = *(const short8*)&as[(wr * 32 + m * 16 + la16) * BK + kk * 32 + kg];
#pragma unroll
      for (int n = 0; n < 4; ++n)
        bf[n] = *(const short8*)&bs[(wc * 64 + n * 16 + la16) * BK + kk * 32 + kg];
#pragma unroll
      for (int m = 0; m < 2; ++m)
#pragma unroll
        for (int n = 0; n < 4; ++n)
          mfma16x16x32(acc[m][n], af[m], bf[n]);
    }
  }
  asm volatile("s_nop 7\n\ts_nop 7");  // MFMA->VALU hazard guard

  const int r0 = brow + wr * 32 + (lane >> 4) * 4;
  const int c0 = bcol + wc * 64 + la16;
  const int64_t b512 = (int64_t)b * 512;

  if (EPI == 4) {
    float* Cb = (float*)Cptr + (int64_t)b * Cbs;
    const float* xb = xres + (int64_t)b * Cbs;
#pragma unroll
    for (int m = 0; m < 2; ++m) {
#pragma unroll
      for (int r = 0; r < 4; ++r) {
        const int row = r0 + m * 16 + r;
        const float scl = v1[row], shf = v2[b512 + row];
#pragma unroll
        for (int n = 0; n < 4; ++n) {
          const int col = c0 + n * 16;
          Cb[(int64_t)row * N + col] = acc[m][n][r] * scl + shf + xb[(int64_t)row * N + col];
        }
      }
    }
  } else {
    u16* Cb = (u16*)Cptr + (int64_t)b * Cbs;
#pragma unroll
    for (int m = 0; m < 2; ++m) {
#pragma unroll
      for (int r = 0; r < 4; ++r) {
        const int row = r0 + m * 16 + r;
        float a1 = 0.f, a3 = 0.f;
        if (EPI == 6) { a1 = v1[b512 + row]; a3 = v3[row]; }
#pragma unroll
        for (int n = 0; n < 4; ++n) {
          const int col = c0 + n * 16;
          float v = acc[m][n][r];
          if (EPI == 6) v += a1 * v2[col] + a3 * v4[b512 + col];
          Cb[(int64_t)row * N + col] = f2bf(v);
        }
      }
    }
  }
}

// ---- f32 row -> bf16 row + row-sum for BOTH x and x_h (grid.y selects) ----
__global__ void cvt_row2(const float* __restrict__ x, const float* __restrict__ xh,
                         u16* __restrict__ xB, u16* __restrict__ xhB,
                         float* __restrict__ rx, float* __restrict__ rxh) {
  const int64_t row = blockIdx.x;
  const float* in = blockIdx.y ? xh : x;
  u16* out = blockIdx.y ? xhB : xB;
  float* rs = blockIdx.y ? rxh : rx;
  const float4* ib = (const float4*)(in + row * 1152);
  U16x4* ob = (U16x4*)(out + row * 1152);
  float s = 0.f;
  for (int i = threadIdx.x; i < 288; i += 256) {
    float4 v = ib[i];
    s += v.x + v.y + v.z + v.w;
    U16x4 o = {f2bf(v.x), f2bf(v.y), f2bf(v.z), f2bf(v.w)};
    ob[i] = o;
  }
  for (int off = 32; off; off >>= 1) s += __shfl_down(s, off);
  __shared__ float red[4];
  if ((threadIdx.x & 63) == 0) red[threadIdx.x >> 6] = s;
  __syncthreads();
  if (threadIdx.x == 0) rs[row] = red[0] + red[1] + red[2] + red[3];
}

// ---- bf16 [C][N] -> bf16 [N][C] per batch ----
__global__ void transpose_bf(const u16* __restrict__ in, u16* __restrict__ out,
                             int C, int N) {
  __shared__ u16 t[32][36];
  const int b = blockIdx.z;
  const u16* ib = in + (int64_t)b * C * N;
  u16* ob = out + (int64_t)b * C * N;
  const int n0 = blockIdx.x * 32, c0 = blockIdx.y * 32;
  const int tr = threadIdx.x >> 3, tc = (threadIdx.x & 7) * 4;
  U16x4 v = *(const U16x4*)&ib[(int64_t)(c0 + tr) * N + n0 + tc];
  t[tr][tc] = v.x; t[tr][tc + 1] = v.y; t[tr][tc + 2] = v.z; t[tr][tc + 3] = v.w;
  __syncthreads();
  U16x4 o = {t[tc][tr], t[tc + 1][tr], t[tc + 2][tr], t[tc + 3][tr]};
  *(U16x4*)&ob[(int64_t)(n0 + tr) * C + c0 + tc] = o;
}

// ---- 4x fused 512x512 f32 -> bf16 transpose (blockIdx.z selects weight) ----
__global__ void transpose_cvt4(const float* __restrict__ s0, const float* __restrict__ s1,
                               const float* __restrict__ s2, const float* __restrict__ s3,
                               u16* __restrict__ d0, u16* __restrict__ d1,
                               u16* __restrict__ d2, u16* __restrict__ d3) {
  const int z = blockIdx.z;
  const float* in = z == 0 ? s0 : z == 1 ? s1 : z == 2 ? s2 : s3;
  u16* out = z == 0 ? d0 : z == 1 ? d1 : z == 2 ? d2 : d3;
  __shared__ float t[32][33];
  const int n0 = blockIdx.x * 32, c0 = blockIdx.y * 32;
  const int tr = threadIdx.x >> 3, tc = (threadIdx.x & 7) * 4;
  const float4 v = *(const float4*)&in[(int64_t)(c0 + tr) * 512 + n0 + tc];
  t[tr][tc] = v.x; t[tr][tc + 1] = v.y; t[tr][tc + 2] = v.z; t[tr][tc + 3] = v.w;
  __syncthreads();
  U16x4 o;
  o.x = f2bf(t[tc][tr]); o.y = f2bf(t[tc + 1][tr]);
  o.z = f2bf(t[tc + 2][tr]); o.w = f2bf(t[tc + 3][tr]);
  *(U16x4*)&out[(int64_t)(n0 + tr) * 512 + c0 + tc] = o;
}

// ---- f32 -> bf16 elementwise ----
__global__ void cvt_kernel(const float* __restrict__ in, u16* __restrict__ out, int n4) {
  const int i = blockIdx.x * 256 + threadIdx.x;
  if (i < n4) {
    const float4 v = ((const float4*)in)[i];
    U16x4 o = {f2bf(v.x), f2bf(v.y), f2bf(v.z), f2bf(v.w)};
    ((U16x4*)out)[i] = o;
  }
}

// ---- batch-independent small vectors + BN prep (all coalesced) ----
__global__ void k_statics(const float* __restrict__ Wp, const u16* __restrict__ WwT,
                          const float* __restrict__ Wg,
                          const float* __restrict__ bg, const float* __restrict__ bt,
                          const float* __restrict__ bp, const float* __restrict__ bw,
                          const float* __restrict__ gamma, const float* __restrict__ beta,
                          const float* __restrict__ mean, const float* __restrict__ var,
                          float* __restrict__ h1, float* __restrict__ w1,
                          float* __restrict__ c2, float* __restrict__ s2,
                          float* __restrict__ scale, float* __restrict__ sc2,
                          float* __restrict__ shift0) {
  const int gid = blockIdx.x * 64 + threadIdx.x;
  if (gid < 512) {                    // h1[j] = sum_k Wp[k,j]*bg[k]  (coalesced)
    float s = 0;
    for (int k = 0; k < 512; ++k) s += Wp[k * 512 + gid] * bg[k];
    h1[gid] = s;
  } else if (gid < 1024) {            // w1[c] = sum_k Ww[c,k]*bt[k] via WwT (coalesced)
    const int c = gid - 512;
    float s = 0;
    for (int k = 0; k < 512; ++k) s += bf2f(WwT[k * 512 + c]) * bt[k];
    w1[c] = s;
  } else if (gid < 1536) {            // c2[e] = sum_k Wg[k,e]*bp[k]  (coalesced)
    const int e = gid - 1024;
    float s = 0;
    for (int k = 0; k < 512; ++k) s += Wg[k * 512 + e] * bp[k];
    c2[e] = s;
  } else if (gid < 2048) {            // BN prep
    const int c = gid - 1536;
    const float sc = gamma[c] * rsqrtf(var[c] + 1e-5f);
    scale[c] = sc;
    sc2[c] = sc * (1.0f / 512.0f);
    shift0[c] = (bw[c] - mean[c]) * sc + beta[c];
  } else {                            // s2 = bp . bg
    const int l = gid - 2048;
    float p = 0;
    for (int k = l; k < 512; k += 64) p += bp[k] * bg[k];
    for (int off = 32; off; off >>= 1) p += __shfl_down(p, off);
    if (l == 0) s2[0] = p;
  }
}

// ---- fused per-batch: sigphi,tau2 then c1,w2,s1 (one block = one batch) ----
__global__ void k_vecs(const u16* __restrict__ WpT, const u16* __restrict__ WtT,
                       const u16* __restrict__ WwT, const float* __restrict__ Wg,
                       const float* __restrict__ bt, const float* __restrict__ bg,
                       const float* __restrict__ rx, const float* __restrict__ rxh,
                       float* __restrict__ sigphi, float* __restrict__ tau2,
                       float* __restrict__ c1, float* __restrict__ w2,
                       float* __restrict__ s1) {
  __shared__ float rxl[512], rxhl[512], spl[512], tal[512];
  __shared__ float red[8];
  const int bb = blockIdx.x, t = threadIdx.x;
  rxl[t] = rx[bb * 512 + t];
  rxhl[t] = rxh[bb * 512 + t];
  __syncthreads();
  float sp = 0, ta = 0;
  for (int d = 0; d < 512; ++d) {
    sp += bf2f(WpT[d * 512 + t]) * rxhl[d];   // Wp[t,d] = WpT[d,t]
    ta += bf2f(WtT[d * 512 + t]) * rxl[d];
  }
  ta += 1152.0f * bt[t];
  spl[t] = sp; tal[t] = ta;
  sigphi[bb * 512 + t] = sp;
  tau2[bb * 512 + t] = ta;
  __syncthreads();
  float c = 0, wv = 0;
  for (int k = 0; k < 512; ++k) {
    c += Wg[k * 512 + t] * spl[k];            // Wg^T coalesced native
    wv += bf2f(WwT[k * 512 + t]) * tal[k];    // Ww[t,k] = WwT[k,t]
  }
  c1[bb * 512 + t] = c;
  w2[bb * 512 + t] = wv;
  float p = spl[t] * bg[t];
  for (int off = 32; off; off >>= 1) p += __shfl_down(p, off);
  if ((t & 63) == 0) red[t >> 6] = p;
  __syncthreads();
  if (t == 0) {
    float s = 0;
    for (int i = 0; i < 8; ++i) s += red[i];
    s1[bb] = s;
  }
}

// ---- per-batch u/v chain -> shiftv (coalesced via transposed weights) ----
__global__ void k_uv(const u16* __restrict__ MT, const float* __restrict__ h1,
                     const u16* __restrict__ WtT, const u16* __restrict__ WwT,
                     const float* __restrict__ bt, const float* __restrict__ tau2,
                     const float* __restrict__ s1, const float* __restrict__ s2,
                     const float* __restrict__ scale, const float* __restrict__ shift0,
                     float* __restrict__ shiftv) {
  __shared__ float h1l[512], m1l[512], ul[512];
  const int bb = blockIdx.x, t = threadIdx.x;
  h1l[t] = h1[t];
  __syncthreads();
  const u16* Mb = MT + (int64_t)bb * 262144;
  float acc = 0;
  for (int j = 0; j < 512; ++j) acc += bf2f(Mb[j * 512 + t]) * h1l[j];
  m1l[t] = acc;
  __syncthreads();
  float u = 0;
  for (int d = 0; d < 512; ++d) u += bf2f(WtT[d * 512 + t]) * m1l[d];
  u = (u + bt[t] * s1[bb] + tau2[bb * 512 + t] * s2[0]) * (1.0f / 512.0f);
  ul[t] = u;
  __syncthreads();
  float v = 0;
  for (int a = 0; a < 512; ++a) v += bf2f(WwT[a * 512 + t]) * ul[a];
  shiftv[bb * 512 + t] = v * scale[t] + shift0[t];
}

extern "C" void kernel_launch(void* const* d_in, const int* in_sizes, int n_in,
                              void* d_out, int out_size, void* d_ws, size_t ws_size,
                              hipStream_t stream) {
  const float* x     = (const float*)d_in[0];
  const float* x_h   = (const float*)d_in[1];
  const float* Wg    = (const float*)d_in[2];
  const float* bg    = (const float*)d_in[3];
  const float* Wt    = (const float*)d_in[4];
  const float* bt    = (const float*)d_in[5];
  const float* Wp    = (const float*)d_in[6];
  const float* bp    = (const float*)d_in[7];
  const float* Ww    = (const float*)d_in[8];
  const float* bw    = (const float*)d_in[9];
  const float* gamma = (const float*)d_in[10];
  const float* beta  = (const float*)d_in[11];
  const float* rmean = (const float*)d_in[12];
  const float* rvar  = (const float*)d_in[13];
  float* out = (float*)d_out;

  const int Bsz = 32, D = 512, N = 1152;
  const int64_t DN = (int64_t)D * N;   // 589824
  const int64_t DD = (int64_t)D * D;   // 262144

  char* ws = (char*)d_ws;
  const size_t KB = 1024, MB = 1048576;
  // weight pairs placed ADJACENT so the Wa/WbT GEMMs run as one z=2 dispatch
  u16* WtT  = (u16*)(ws + 0);            // pair B: [WtT, WpT]
  u16* WpT  = (u16*)(ws + 512 * KB);
  u16* WwB  = (u16*)(ws + 1 * MB);       // pair A: [WwB, WgT]
  u16* WgT  = (u16*)(ws + 1 * MB + 512 * KB);
  u16* WaB  = (u16*)(ws + 2 * MB);       // pair C: [Wa, WbT]
  u16* WbTB = (u16*)(ws + 2 * MB + 512 * KB);
  u16* WwT  = (u16*)(ws + 3 * MB);
  float* rx     = (float*)(ws + 3 * MB + 512 * KB);
  float* rxh    = (float*)(ws + 3 * MB + 576 * KB);
  float* sigphi = (float*)(ws + 3 * MB + 640 * KB);
  float* tau2   = (float*)(ws + 3 * MB + 704 * KB);
  float* c1     = (float*)(ws + 3 * MB + 768 * KB);
  float* w2     = (float*)(ws + 3 * MB + 832 * KB);
  float* shiftv = (float*)(ws + 3 * MB + 896 * KB);
  float* h1     = (float*)(ws + 3 * MB + 960 * KB);
  float* w1     = (float*)(ws + 3 * MB + 962 * KB);
  float* c2     = (float*)(ws + 3 * MB + 964 * KB);
  float* scale  = (float*)(ws + 3 * MB + 966 * KB);
  float* sc2    = (float*)(ws + 3 * MB + 968 * KB);
  float* shift0 = (float*)(ws + 3 * MB + 970 * KB);
  float* s1     = (float*)(ws + 3 * MB + 972 * KB);
  float* s2     = (float*)(ws + 3 * MB + 974 * KB);
  u16* xB  = (u16*)(ws + 4 * MB);                  // 36 MB
  u16* xhB = (u16*)(ws + 40 * MB);                 // 36 MB
  u16* xhT = (u16*)(ws + 76 * MB);                 // 36 MB
  u16* SD1 = (u16*)(ws + 112 * MB);                // 17 MB (MT -> Q)
  u16* SD2 = (u16*)(ws + 130 * MB);                // 17 MB (R)

  // --- prep ---
  cvt_row2<<<dim3(Bsz * D, 2), 256, 0, stream>>>(x, x_h, xB, xhB, rx, rxh);
  transpose_bf<<<dim3(N / 32, D / 32, Bsz), 256, 0, stream>>>(xhB, xhT, D, N);
  transpose_cvt4<<<dim3(16, 16, 4), 256, 0, stream>>>(Wt, Wp, Wg, Ww, WtT, WpT, WgT, WwT);
  cvt_kernel<<<dim3(D * D / 4 / 256), 256, 0, stream>>>(Ww, WwB, D * D / 4);
  k_statics<<<dim3(33), 64, 0, stream>>>(Wp, WwT, Wg, bg, bt, bp, bw, gamma, beta,
                                         rmean, rvar, h1, w1, c2, s2, scale, sc2, shift0);
  k_vecs<<<dim3(Bsz), 512, 0, stream>>>(WpT, WtT, WwT, Wg, bt, bg, rx, rxh,
                                        sigphi, tau2, c1, w2, s1);
  // Wa = Ww*Wt (b=0) ; WbT[e,j] = sum_k Wg[k,e]Wp[k,j] (b=1) — one dispatch
  gemm_abt<0><<<dim3(4, 4, 2), 512, 0, stream>>>(
      WwB, DD, WtT, DD, WaB, DD, D, D, D, nullptr, nullptr, nullptr, nullptr, nullptr);

  // --- main chain ---
  // G1: MT[j,i] = sum_n x_h[j,n] x[i,n]
  gemm_abt<0><<<dim3(4, 4, Bsz), 512, 0, stream>>>(
      xhB, DN, xB, DN, SD1, DD, D, D, N, nullptr, nullptr, nullptr, nullptr, nullptr);
  // shiftv (reads MT)
  k_uv<<<dim3(Bsz), 512, 0, stream>>>(SD1, h1, WtT, WwT, bt, tau2, s1, s2,
                                      scale, shift0, shiftv);
  // G2: R[p,j] = sum_i Wa[p,i] MT[j,i]
  gemm_abt<0><<<dim3(4, 4, Bsz), 512, 0, stream>>>(
      WaB, 0, SD1, DD, SD2, DD, D, D, D, nullptr, nullptr, nullptr, nullptr, nullptr);
  // G3: Q[p,e] = sum_j R[p,j] WbT[e,j] + rank-2 bias correction
  gemm_abt<6><<<dim3(4, 4, Bsz), 512, 0, stream>>>(
      SD2, DD, WbTB, 0, SD1, DD, D, D, D, w2, c2, w1, c1, nullptr);
  // G6: out[c,n] = sc2[c]*sum_e Q[c,e] xhT[n,e] + shiftv[b,c] + x[b,c,n]
  gemm_abt<4><<<dim3(N / 128, 4, Bsz), 512, 0, stream>>>(
      SD1, DD, xhT, DN, out, DN, D, N, D, sc2, shiftv, nullptr, nullptr, x);
}

// Round 5
// 312.687 us; speedup vs baseline: 1.1324x; 1.1324x over previous
//
#include <hip/hip_runtime.h>
#include <stdint.h>

typedef short short8 __attribute__((ext_vector_type(8)));
typedef float f32x4 __attribute__((ext_vector_type(4)));
typedef unsigned short u16;
typedef unsigned int u32;

struct alignas(8) U16x4 { u16 x, y, z, w; };

__device__ __forceinline__ u16 f2bf(float f) {
  u32 u = __float_as_uint(f);
  u += 0x7fffu + ((u >> 16) & 1u);
  return (u16)(u >> 16);
}
__device__ __forceinline__ float bf2f(u16 v) {
  return __uint_as_float(((u32)v) << 16);
}

__device__ __forceinline__ void gld_lds16(const u16* g, u16* l) {
  __builtin_amdgcn_global_load_lds((const __attribute__((address_space(1))) u32*)g,
                                   (__attribute__((address_space(3))) u32*)l,
                                   16, 0, 0);
}

__device__ __forceinline__ void mfma16x16x32(f32x4& c, short8 a, short8 b) {
  asm("v_mfma_f32_16x16x32_bf16 %0, %1, %2, %0" : "+v"(c) : "v"(a), "v"(b));
}

// ---------------------------------------------------------------------------
// Batched C = A * B^T (A:[M,K] rm, Bt:[N,K] rm). 512 threads (8 waves, wave
// tile 32x64), BK=64, double-buffered LDS, counted-vmcnt pipeline.
// T2: LDS XOR-swizzle (16B slot ^= row&7) — linear LDS dest (global_load_lds
//     rule #21), inverse-swizzled GLOBAL source, swizzled ds_read.
// T1: when gridDim.z==1, flat grid decoded so batch z runs on XCD z%8
//     (batch working set ~4MB fits one XCD L2). Bijective for grids %8==0.
// EPI 0: bf16 out; EPI 6: bf16 + v1[b512+row]*v2[col] + v3[row]*v4[b512+col];
// EPI 4: f32 out, acc*v1[row] + v2[b512+row] + xres[b][row][col]
// ---------------------------------------------------------------------------
template<int EPI>
__global__ void __launch_bounds__(512, 4) gemm_abt(
                         const u16* __restrict__ A, int64_t Abs,
                         const u16* __restrict__ Bt, int64_t Bbs,
                         void* __restrict__ Cptr, int64_t Cbs,
                         int M, int N, int K,
                         const float* __restrict__ v1,
                         const float* __restrict__ v2,
                         const float* __restrict__ v3,
                         const float* __restrict__ v4,
                         const float* __restrict__ xres) {
  constexpr int BM = 128, BN = 128, BK = 64;
  __shared__ u16 As[2][BM * BK];
  __shared__ u16 Bs[2][BN * BK];

  int bx, by, b;
  if (gridDim.z == 1) {            // T1: XCD-aware flat decode
    const int nbx = N >> 7;
    const int bpb = nbx * (M >> 7);
    const int id = blockIdx.x;
    const int xcd = id & 7, rest = id >> 3;
    b = xcd + 8 * (rest / bpb);
    const int wi = rest % bpb;
    by = wi / nbx; bx = wi % nbx;
  } else {
    bx = blockIdx.x; by = blockIdx.y; b = blockIdx.z;
  }

  const u16* Ab = A + (int64_t)b * Abs;
  const u16* Bb = Bt + (int64_t)b * Bbs;
  const int brow = by * BM, bcol = bx * BN;
  const int tid = threadIdx.x, lane = tid & 63, w = tid >> 6;
  const int wr = w >> 1, wc = w & 1;  // 4x2 wave grid; wave tile 32 rows x 64 cols

  f32x4 acc[2][4] = {};

  // staging: thread t -> rows (t>>3) and (t>>3)+64.  LDS dest LINEAR
  // (t*16B); global source column pre-swizzled: chunk ^= (row&7)  (rule #21).
  const int sr = tid >> 3;
  const int scs = ((tid & 7) ^ (sr & 7)) * 8;   // swizzled source col (elems)
  u16* lA0 = &As[0][sr * BK + (tid & 7) * 8];
  u16* lB0 = &Bs[0][sr * BK + (tid & 7) * 8];
  const u16* gA = Ab + (int64_t)(brow + sr) * K + scs;
  const u16* gB = Bb + (int64_t)(bcol + sr) * K + scs;

  const int la16 = lane & 15;
  const int kg = (lane >> 4) * 8;
  const int swz = (la16 & 7) * 8;    // ds_read XOR (elems; 16B granules)
  const int nt = K / BK;

  // prologue: stage tile 0 into buf 0
  gld_lds16(gA, lA0);
  gld_lds16(gA + (int64_t)64 * K, lA0 + 64 * BK);
  gld_lds16(gB, lB0);
  gld_lds16(gB + (int64_t)64 * K, lB0 + 64 * BK);

  for (int t = 0; t < nt; ++t) {
    __builtin_amdgcn_s_barrier();  // prev iter's LDS reads done before overwrite
    if (t + 1 < nt) {
      const int nb = (t + 1) & 1;
      const int k0 = (t + 1) * BK;
      u16* la = lA0 + nb * BM * BK;
      u16* lb = lB0 + nb * BN * BK;
      gld_lds16(gA + k0, la);
      gld_lds16(gA + (int64_t)64 * K + k0, la + 64 * BK);
      gld_lds16(gB + k0, lb);
      gld_lds16(gB + (int64_t)64 * K + k0, lb + 64 * BK);
      asm volatile("s_waitcnt vmcnt(4)" ::: "memory");  // tile t landed; next in flight
    } else {
      asm volatile("s_waitcnt vmcnt(0)" ::: "memory");
    }
    __builtin_amdgcn_s_barrier();
    __builtin_amdgcn_sched_barrier(0);
    const u16* as = As[t & 1];
    const u16* bs = Bs[t & 1];
#pragma unroll
    for (int kk = 0; kk < 2; ++kk) {
      short8 af[2], bf[4];
      const int kc = (kk * 32 + kg) ^ swz;   // swizzled k-chunk
#pragma unroll
      for (int m = 0; m < 2; ++m)
        af[m] = *(const short8*)&as[(wr * 32 + m * 16 + la16) * BK + kc];
#pragma unroll
      for (int n = 0; n < 4; ++n)
        bf[n] = *(const short8*)&bs[(wc * 64 + n * 16 + la16) * BK + kc];
#pragma unroll
      for (int m = 0; m < 2; ++m)
#pragma unroll
        for (int n = 0; n < 4; ++n)
          mfma16x16x32(acc[m][n], af[m], bf[n]);
    }
  }
  asm volatile("s_nop 7\n\ts_nop 7");  // MFMA->VALU hazard guard

  const int r0 = brow + wr * 32 + (lane >> 4) * 4;
  const int c0 = bcol + wc * 64 + la16;
  const int64_t b512 = (int64_t)b * 512;

  if (EPI == 4) {
    float* Cb = (float*)Cptr + (int64_t)b * Cbs;
    const float* xb = xres + (int64_t)b * Cbs;
#pragma unroll
    for (int m = 0; m < 2; ++m) {
#pragma unroll
      for (int r = 0; r < 4; ++r) {
        const int row = r0 + m * 16 + r;
        const float scl = v1[row], shf = v2[b512 + row];
#pragma unroll
        for (int n = 0; n < 4; ++n) {
          const int col = c0 + n * 16;
          Cb[(int64_t)row * N + col] = acc[m][n][r] * scl + shf + xb[(int64_t)row * N + col];
        }
      }
    }
  } else {
    u16* Cb = (u16*)Cptr + (int64_t)b * Cbs;
#pragma unroll
    for (int m = 0; m < 2; ++m) {
#pragma unroll
      for (int r = 0; r < 4; ++r) {
        const int row = r0 + m * 16 + r;
        float a1 = 0.f, a3 = 0.f;
        if (EPI == 6) { a1 = v1[b512 + row]; a3 = v3[row]; }
#pragma unroll
        for (int n = 0; n < 4; ++n) {
          const int col = c0 + n * 16;
          float v = acc[m][n][r];
          if (EPI == 6) v += a1 * v2[col] + a3 * v4[b512 + col];
          Cb[(int64_t)row * N + col] = f2bf(v);
        }
      }
    }
  }
}

// ---- f32 row -> bf16 row + row-sum (x only).  One block per row. ----
__global__ void cvt_row(const float* __restrict__ in, u16* __restrict__ out,
                        float* __restrict__ rowsum) {
  const int64_t row = blockIdx.x;
  const float4* ib = (const float4*)(in + row * 1152);
  U16x4* ob = (U16x4*)(out + row * 1152);
  float s = 0.f;
  for (int i = threadIdx.x; i < 288; i += 256) {
    float4 v = ib[i];
    s += v.x + v.y + v.z + v.w;
    U16x4 o = {f2bf(v.x), f2bf(v.y), f2bf(v.z), f2bf(v.w)};
    ob[i] = o;
  }
  for (int off = 32; off; off >>= 1) s += __shfl_down(s, off);
  __shared__ float red[4];
  if ((threadIdx.x & 63) == 0) red[threadIdx.x >> 6] = s;
  __syncthreads();
  if (threadIdx.x == 0) rowsum[row] = red[0] + red[1] + red[2] + red[3];
}

// ---- x_h: f32 [C][N] -> bf16 [C][N] + bf16 [N][C] + partial rowsums ----
// grid (36,16,32) x 256 thr; 32x32 tiles; no atomics (partials reduced later).
__global__ void prep_xh(const float* __restrict__ xh, u16* __restrict__ xhB,
                        u16* __restrict__ xhT, float* __restrict__ rxh_part) {
  __shared__ float tl[32][33];
  const int b = blockIdx.z;
  const int n0 = blockIdx.x * 32, c0 = blockIdx.y * 32;
  const float* ib = xh + (int64_t)b * 589824;
  const int tr = threadIdx.x >> 3, tc = (threadIdx.x & 7) * 4;
  const float4 v = *(const float4*)&ib[(int64_t)(c0 + tr) * 1152 + n0 + tc];
  tl[tr][tc] = v.x; tl[tr][tc + 1] = v.y; tl[tr][tc + 2] = v.z; tl[tr][tc + 3] = v.w;
  U16x4 o = {f2bf(v.x), f2bf(v.y), f2bf(v.z), f2bf(v.w)};
  *(U16x4*)&xhB[(int64_t)b * 589824 + (int64_t)(c0 + tr) * 1152 + n0 + tc] = o;
  __syncthreads();
  U16x4 ot = {f2bf(tl[tc][tr]), f2bf(tl[tc + 1][tr]),
              f2bf(tl[tc + 2][tr]), f2bf(tl[tc + 3][tr])};
  *(U16x4*)&xhT[(int64_t)b * 589824 + (int64_t)(n0 + tr) * 512 + c0 + tc] = ot;
  if (threadIdx.x < 32) {
    float s = 0;
#pragma unroll
    for (int c = 0; c < 32; ++c) s += tl[threadIdx.x][c];
    rxh_part[(n0 >> 5) * 16384 + b * 512 + c0 + threadIdx.x] = s;
  }
}

// ---- 4x fused 512x512 f32 -> bf16 transpose (blockIdx.z selects weight) ----
__global__ void transpose_cvt4(const float* __restrict__ s0, const float* __restrict__ s1,
                               const float* __restrict__ s2, const float* __restrict__ s3,
                               u16* __restrict__ d0, u16* __restrict__ d1,
                               u16* __restrict__ d2, u16* __restrict__ d3) {
  const int z = blockIdx.z;
  const float* in = z == 0 ? s0 : z == 1 ? s1 : z == 2 ? s2 : s3;
  u16* out = z == 0 ? d0 : z == 1 ? d1 : z == 2 ? d2 : d3;
  __shared__ float t[32][33];
  const int n0 = blockIdx.x * 32, c0 = blockIdx.y * 32;
  const int tr = threadIdx.x >> 3, tc = (threadIdx.x & 7) * 4;
  const float4 v = *(const float4*)&in[(int64_t)(c0 + tr) * 512 + n0 + tc];
  t[tr][tc] = v.x; t[tr][tc + 1] = v.y; t[tr][tc + 2] = v.z; t[tr][tc + 3] = v.w;
  __syncthreads();
  U16x4 o;
  o.x = f2bf(t[tc][tr]); o.y = f2bf(t[tc + 1][tr]);
  o.z = f2bf(t[tc + 2][tr]); o.w = f2bf(t[tc + 3][tr]);
  *(U16x4*)&out[(int64_t)(n0 + tr) * 512 + c0 + tc] = o;
}

// ---- f32 -> bf16 elementwise ----
__global__ void cvt_kernel(const float* __restrict__ in, u16* __restrict__ out, int n4) {
  const int i = blockIdx.x * 256 + threadIdx.x;
  if (i < n4) {
    const float4 v = ((const float4*)in)[i];
    U16x4 o = {f2bf(v.x), f2bf(v.y), f2bf(v.z), f2bf(v.w)};
    ((U16x4*)out)[i] = o;
  }
}

// ---- batch-independent small vectors + BN prep (all coalesced) ----
__global__ void k_statics(const float* __restrict__ Wp, const u16* __restrict__ WwT,
                          const float* __restrict__ Wg,
                          const float* __restrict__ bg, const float* __restrict__ bt,
                          const float* __restrict__ bp, const float* __restrict__ bw,
                          const float* __restrict__ gamma, const float* __restrict__ beta,
                          const float* __restrict__ mean, const float* __restrict__ var,
                          float* __restrict__ h1, float* __restrict__ w1,
                          float* __restrict__ c2, float* __restrict__ s2,
                          float* __restrict__ scale, float* __restrict__ sc2,
                          float* __restrict__ shift0) {
  const int gid = blockIdx.x * 64 + threadIdx.x;
  if (gid < 512) {                    // h1[j] = sum_k Wp[k,j]*bg[k]
    float s = 0;
    for (int k = 0; k < 512; ++k) s += Wp[k * 512 + gid] * bg[k];
    h1[gid] = s;
  } else if (gid < 1024) {            // w1[c] = sum_k Ww[c,k]*bt[k] via WwT
    const int c = gid - 512;
    float s = 0;
    for (int k = 0; k < 512; ++k) s += bf2f(WwT[k * 512 + c]) * bt[k];
    w1[c] = s;
  } else if (gid < 1536) {            // c2[e] = sum_k Wg[k,e]*bp[k]
    const int e = gid - 1024;
    float s = 0;
    for (int k = 0; k < 512; ++k) s += Wg[k * 512 + e] * bp[k];
    c2[e] = s;
  } else if (gid < 2048) {            // BN prep
    const int c = gid - 1536;
    const float sc = gamma[c] * rsqrtf(var[c] + 1e-5f);
    scale[c] = sc;
    sc2[c] = sc * (1.0f / 512.0f);
    shift0[c] = (bw[c] - mean[c]) * sc + beta[c];
  } else {                            // s2 = bp . bg
    const int l = gid - 2048;
    float p = 0;
    for (int k = l; k < 512; k += 64) p += bp[k] * bg[k];
    for (int off = 32; off; off >>= 1) p += __shfl_down(p, off);
    if (l == 0) s2[0] = p;
  }
}

// ---- fused per-batch: sigphi,tau2 then c1,w2,s1 (one block = one batch) ----
__global__ void k_vecs(const u16* __restrict__ WpT, const u16* __restrict__ WtT,
                       const u16* __restrict__ WwT, const float* __restrict__ Wg,
                       const float* __restrict__ bt, const float* __restrict__ bg,
                       const float* __restrict__ rx, const float* __restrict__ rxh_part,
                       float* __restrict__ sigphi, float* __restrict__ tau2,
                       float* __restrict__ c1, float* __restrict__ w2,
                       float* __restrict__ s1) {
  __shared__ float rxl[512], rxhl[512], spl[512], tal[512];
  __shared__ float red[8];
  const int bb = blockIdx.x, t = threadIdx.x;
  rxl[t] = rx[bb * 512 + t];
  float rh = 0;
  for (int s = 0; s < 36; ++s) rh += rxh_part[s * 16384 + bb * 512 + t];
  rxhl[t] = rh;
  __syncthreads();
  float sp = 0, ta = 0;
  for (int d = 0; d < 512; ++d) {
    sp += bf2f(WpT[d * 512 + t]) * rxhl[d];   // Wp[t,d] = WpT[d,t]
    ta += bf2f(WtT[d * 512 + t]) * rxl[d];
  }
  ta += 1152.0f * bt[t];
  spl[t] = sp; tal[t] = ta;
  sigphi[bb * 512 + t] = sp;
  tau2[bb * 512 + t] = ta;
  __syncthreads();
  float c = 0, wv = 0;
  for (int k = 0; k < 512; ++k) {
    c += Wg[k * 512 + t] * spl[k];
    wv += bf2f(WwT[k * 512 + t]) * tal[k];
  }
  c1[bb * 512 + t] = c;
  w2[bb * 512 + t] = wv;
  float p = spl[t] * bg[t];
  for (int off = 32; off; off >>= 1) p += __shfl_down(p, off);
  if ((t & 63) == 0) red[t >> 6] = p;
  __syncthreads();
  if (t == 0) {
    float s = 0;
    for (int i = 0; i < 8; ++i) s += red[i];
    s1[bb] = s;
  }
}

// ---- per-batch u/v chain -> shiftv (coalesced via transposed weights) ----
__global__ void k_uv(const u16* __restrict__ MT, const float* __restrict__ h1,
                     const u16* __restrict__ WtT, const u16* __restrict__ WwT,
                     const float* __restrict__ bt, const float* __restrict__ tau2,
                     const float* __restrict__ s1, const float* __restrict__ s2,
                     const float* __restrict__ scale, const float* __restrict__ shift0,
                     float* __restrict__ shiftv) {
  __shared__ float h1l[512], m1l[512], ul[512];
  const int bb = blockIdx.x, t = threadIdx.x;
  h1l[t] = h1[t];
  __syncthreads();
  const u16* Mb = MT + (int64_t)bb * 262144;
  float acc = 0;
  for (int j = 0; j < 512; ++j) acc += bf2f(Mb[j * 512 + t]) * h1l[j];
  m1l[t] = acc;
  __syncthreads();
  float u = 0;
  for (int d = 0; d < 512; ++d) u += bf2f(WtT[d * 512 + t]) * m1l[d];
  u = (u + bt[t] * s1[bb] + tau2[bb * 512 + t] * s2[0]) * (1.0f / 512.0f);
  ul[t] = u;
  __syncthreads();
  float v = 0;
  for (int a = 0; a < 512; ++a) v += bf2f(WwT[a * 512 + t]) * ul[a];
  shiftv[bb * 512 + t] = v * scale[t] + shift0[t];
}

extern "C" void kernel_launch(void* const* d_in, const int* in_sizes, int n_in,
                              void* d_out, int out_size, void* d_ws, size_t ws_size,
                              hipStream_t stream) {
  const float* x     = (const float*)d_in[0];
  const float* x_h   = (const float*)d_in[1];
  const float* Wg    = (const float*)d_in[2];
  const float* bg    = (const float*)d_in[3];
  const float* Wt    = (const float*)d_in[4];
  const float* bt    = (const float*)d_in[5];
  const float* Wp    = (const float*)d_in[6];
  const float* bp    = (const float*)d_in[7];
  const float* Ww    = (const float*)d_in[8];
  const float* bw    = (const float*)d_in[9];
  const float* gamma = (const float*)d_in[10];
  const float* beta  = (const float*)d_in[11];
  const float* rmean = (const float*)d_in[12];
  const float* rvar  = (const float*)d_in[13];
  float* out = (float*)d_out;

  const int Bsz = 32, D = 512, N = 1152;
  const int64_t DN = (int64_t)D * N;   // 589824
  const int64_t DD = (int64_t)D * D;   // 262144

  char* ws = (char*)d_ws;
  const size_t KB = 1024, MB = 1048576;
  u16* WtT  = (u16*)(ws + 0);            // pair B: [WtT, WpT]
  u16* WpT  = (u16*)(ws + 512 * KB);
  u16* WwB  = (u16*)(ws + 1 * MB);       // pair A: [WwB, WgT]
  u16* WgT  = (u16*)(ws + 1 * MB + 512 * KB);
  u16* WaB  = (u16*)(ws + 2 * MB);       // pair C: [Wa, WbT]
  u16* WbTB = (u16*)(ws + 2 * MB + 512 * KB);
  u16* WwT  = (u16*)(ws + 3 * MB);
  float* rx     = (float*)(ws + 3 * MB + 512 * KB);
  float* sigphi = (float*)(ws + 3 * MB + 640 * KB);
  float* tau2   = (float*)(ws + 3 * MB + 704 * KB);
  float* c1     = (float*)(ws + 3 * MB + 768 * KB);
  float* w2     = (float*)(ws + 3 * MB + 832 * KB);
  float* shiftv = (float*)(ws + 3 * MB + 896 * KB);
  float* h1     = (float*)(ws + 3 * MB + 960 * KB);
  float* w1     = (float*)(ws + 3 * MB + 962 * KB);
  float* c2     = (float*)(ws + 3 * MB + 964 * KB);
  float* scale  = (float*)(ws + 3 * MB + 966 * KB);
  float* sc2    = (float*)(ws + 3 * MB + 968 * KB);
  float* shift0 = (float*)(ws + 3 * MB + 970 * KB);
  float* s1     = (float*)(ws + 3 * MB + 972 * KB);
  float* s2     = (float*)(ws + 3 * MB + 974 * KB);
  u16* xB  = (u16*)(ws + 4 * MB);                  // 36 MB
  u16* xhB = (u16*)(ws + 40 * MB);                 // 36 MB
  u16* xhT = (u16*)(ws + 76 * MB);                 // 36 MB
  u16* SD1 = (u16*)(ws + 112 * MB);                // 17 MB (MT -> Q)
  u16* SD2 = (u16*)(ws + 130 * MB);                // 17 MB (R)
  float* rxh_part = (float*)(ws + 148 * MB);       // 36*32*512*4 = 2.25 MB

  // --- prep ---
  cvt_row<<<dim3(Bsz * D), 256, 0, stream>>>(x, xB, rx);
  prep_xh<<<dim3(36, 16, Bsz), 256, 0, stream>>>(x_h, xhB, xhT, rxh_part);
  transpose_cvt4<<<dim3(16, 16, 4), 256, 0, stream>>>(Wt, Wp, Wg, Ww, WtT, WpT, WgT, WwT);
  cvt_kernel<<<dim3(D * D / 4 / 256), 256, 0, stream>>>(Ww, WwB, D * D / 4);
  k_statics<<<dim3(33), 64, 0, stream>>>(Wp, WwT, Wg, bg, bt, bp, bw, gamma, beta,
                                         rmean, rvar, h1, w1, c2, s2, scale, sc2, shift0);
  k_vecs<<<dim3(Bsz), 512, 0, stream>>>(WpT, WtT, WwT, Wg, bt, bg, rx, rxh_part,
                                        sigphi, tau2, c1, w2, s1);
  // Wa = Ww*Wt (b=0) ; WbT[e,j] = sum_k Wg[k,e]Wp[k,j] (b=1) — one dispatch (z-path)
  gemm_abt<0><<<dim3(4, 4, 2), 512, 0, stream>>>(
      WwB, DD, WtT, DD, WaB, DD, D, D, D, nullptr, nullptr, nullptr, nullptr, nullptr);

  // --- main chain (flat grids, XCD-batch swizzled) ---
  // G1: MT[j,i] = sum_n x_h[j,n] x[i,n]
  gemm_abt<0><<<dim3(16 * Bsz), 512, 0, stream>>>(
      xhB, DN, xB, DN, SD1, DD, D, D, N, nullptr, nullptr, nullptr, nullptr, nullptr);
  // shiftv (reads MT)
  k_uv<<<dim3(Bsz), 512, 0, stream>>>(SD1, h1, WtT, WwT, bt, tau2, s1, s2,
                                      scale, shift0, shiftv);
  // G2: R[p,j] = sum_i Wa[p,i] MT[j,i]
  gemm_abt<0><<<dim3(16 * Bsz), 512, 0, stream>>>(
      WaB, 0, SD1, DD, SD2, DD, D, D, D, nullptr, nullptr, nullptr, nullptr, nullptr);
  // G3: Q[p,e] = sum_j R[p,j] WbT[e,j] + rank-2 bias correction
  gemm_abt<6><<<dim3(16 * Bsz), 512, 0, stream>>>(
      SD2, DD, WbTB, 0, SD1, DD, D, D, D, w2, c2, w1, c1, nullptr);
  // G6: out[c,n] = sc2[c]*sum_e Q[c,e] xhT[n,e] + shiftv[b,c] + x[b,c,n]
  gemm_abt<4><<<dim3(36 * Bsz), 512, 0, stream>>>(
      SD1, DD, xhT, DN, out, DN, D, N, D, sc2, shiftv, nullptr, nullptr, x);
}

// Round 6
// 207.734 us; speedup vs baseline: 1.7045x; 1.5052x over previous
//
#include <hip/hip_runtime.h>
#include <stdint.h>

typedef short short8 __attribute__((ext_vector_type(8)));
typedef float f32x4 __attribute__((ext_vector_type(4)));
typedef unsigned short u16;
typedef unsigned int u32;

struct alignas(8) U16x4 { u16 x, y, z, w; };

__device__ __forceinline__ u16 f2bf(float f) {
  u32 u = __float_as_uint(f);
  u += 0x7fffu + ((u >> 16) & 1u);
  return (u16)(u >> 16);
}
__device__ __forceinline__ float bf2f(u16 v) {
  return __uint_as_float(((u32)v) << 16);
}

__device__ __forceinline__ void gld_lds16(const u16* g, u16* l) {
  __builtin_amdgcn_global_load_lds((const __attribute__((address_space(1))) u32*)g,
                                   (__attribute__((address_space(3))) u32*)l,
                                   16, 0, 0);
}

__device__ __forceinline__ void mfma16x16x32(f32x4& c, short8 a, short8 b) {
  asm("v_mfma_f32_16x16x32_bf16 %0, %1, %2, %0" : "+v"(c) : "v"(a), "v"(b));
}

__device__ __forceinline__ float wave_red(float v) {
  for (int off = 32; off; off >>= 1) v += __shfl_down(v, off);
  return v;
}

// ---------------------------------------------------------------------------
// Batched C = A * B^T (A:[M,K] rm, Bt:[N,K] rm). 512 threads (8 waves, wave
// tile 32x64), BK=64, double-buffered LDS, counted-vmcnt pipeline.
// T2: LDS XOR-swizzle; linear LDS dest, inverse-swizzled global src (rule #21).
// T1: when gridDim.z==1, flat grid decoded so batch z runs on XCD z%8.
// EPI 0: bf16 out; EPI 6: bf16 + v1[b512+row]*v2[col] + v3[row]*v4[b512+col];
// EPI 4: f32 out, acc*v1[row] + v2[b512+row] + xres[b][row][col]
// ---------------------------------------------------------------------------
template<int EPI>
__global__ void __launch_bounds__(512, 4) gemm_abt(
                         const u16* __restrict__ A, int64_t Abs,
                         const u16* __restrict__ Bt, int64_t Bbs,
                         void* __restrict__ Cptr, int64_t Cbs,
                         int M, int N, int K,
                         const float* __restrict__ v1,
                         const float* __restrict__ v2,
                         const float* __restrict__ v3,
                         const float* __restrict__ v4,
                         const float* __restrict__ xres) {
  constexpr int BM = 128, BN = 128, BK = 64;
  __shared__ u16 As[2][BM * BK];
  __shared__ u16 Bs[2][BN * BK];

  int bx, by, b;
  if (gridDim.z == 1) {            // T1: XCD-aware flat decode
    const int nbx = N >> 7;
    const int bpb = nbx * (M >> 7);
    const int id = blockIdx.x;
    const int xcd = id & 7, rest = id >> 3;
    b = xcd + 8 * (rest / bpb);
    const int wi = rest % bpb;
    by = wi / nbx; bx = wi % nbx;
  } else {
    bx = blockIdx.x; by = blockIdx.y; b = blockIdx.z;
  }

  const u16* Ab = A + (int64_t)b * Abs;
  const u16* Bb = Bt + (int64_t)b * Bbs;
  const int brow = by * BM, bcol = bx * BN;
  const int tid = threadIdx.x, lane = tid & 63, w = tid >> 6;
  const int wr = w >> 1, wc = w & 1;  // 4x2 wave grid; wave tile 32 rows x 64 cols

  f32x4 acc[2][4] = {};

  const int sr = tid >> 3;
  const int scs = ((tid & 7) ^ (sr & 7)) * 8;   // swizzled source col (elems)
  u16* lA0 = &As[0][sr * BK + (tid & 7) * 8];
  u16* lB0 = &Bs[0][sr * BK + (tid & 7) * 8];
  const u16* gA = Ab + (int64_t)(brow + sr) * K + scs;
  const u16* gB = Bb + (int64_t)(bcol + sr) * K + scs;

  const int la16 = lane & 15;
  const int kg = (lane >> 4) * 8;
  const int swz = (la16 & 7) * 8;    // ds_read XOR (elems; 16B granules)
  const int nt = K / BK;

  gld_lds16(gA, lA0);
  gld_lds16(gA + (int64_t)64 * K, lA0 + 64 * BK);
  gld_lds16(gB, lB0);
  gld_lds16(gB + (int64_t)64 * K, lB0 + 64 * BK);

  for (int t = 0; t < nt; ++t) {
    __builtin_amdgcn_s_barrier();  // prev iter's LDS reads done before overwrite
    if (t + 1 < nt) {
      const int nb = (t + 1) & 1;
      const int k0 = (t + 1) * BK;
      u16* la = lA0 + nb * BM * BK;
      u16* lb = lB0 + nb * BN * BK;
      gld_lds16(gA + k0, la);
      gld_lds16(gA + (int64_t)64 * K + k0, la + 64 * BK);
      gld_lds16(gB + k0, lb);
      gld_lds16(gB + (int64_t)64 * K + k0, lb + 64 * BK);
      asm volatile("s_waitcnt vmcnt(4)" ::: "memory");  // tile t landed; next in flight
    } else {
      asm volatile("s_waitcnt vmcnt(0)" ::: "memory");
    }
    __builtin_amdgcn_s_barrier();
    __builtin_amdgcn_sched_barrier(0);
    const u16* as = As[t & 1];
    const u16* bs = Bs[t & 1];
#pragma unroll
    for (int kk = 0; kk < 2; ++kk) {
      short8 af[2], bf[4];
      const int kc = (kk * 32 + kg) ^ swz;   // swizzled k-chunk
#pragma unroll
      for (int m = 0; m < 2; ++m)
        af[m] = *(const short8*)&as[(wr * 32 + m * 16 + la16) * BK + kc];
#pragma unroll
      for (int n = 0; n < 4; ++n)
        bf[n] = *(const short8*)&bs[(wc * 64 + n * 16 + la16) * BK + kc];
#pragma unroll
      for (int m = 0; m < 2; ++m)
#pragma unroll
        for (int n = 0; n < 4; ++n)
          mfma16x16x32(acc[m][n], af[m], bf[n]);
    }
  }
  asm volatile("s_nop 7\n\ts_nop 7");  // MFMA->VALU hazard guard

  const int r0 = brow + wr * 32 + (lane >> 4) * 4;
  const int c0 = bcol + wc * 64 + la16;
  const int64_t b512 = (int64_t)b * 512;

  if (EPI == 4) {
    float* Cb = (float*)Cptr + (int64_t)b * Cbs;
    const float* xb = xres + (int64_t)b * Cbs;
#pragma unroll
    for (int m = 0; m < 2; ++m) {
#pragma unroll
      for (int r = 0; r < 4; ++r) {
        const int row = r0 + m * 16 + r;
        const float scl = v1[row], shf = v2[b512 + row];
#pragma unroll
        for (int n = 0; n < 4; ++n) {
          const int col = c0 + n * 16;
          Cb[(int64_t)row * N + col] = acc[m][n][r] * scl + shf + xb[(int64_t)row * N + col];
        }
      }
    }
  } else {
    u16* Cb = (u16*)Cptr + (int64_t)b * Cbs;
#pragma unroll
    for (int m = 0; m < 2; ++m) {
#pragma unroll
      for (int r = 0; r < 4; ++r) {
        const int row = r0 + m * 16 + r;
        float a1 = 0.f, a3 = 0.f;
        if (EPI == 6) { a1 = v1[b512 + row]; a3 = v3[row]; }
#pragma unroll
        for (int n = 0; n < 4; ++n) {
          const int col = c0 + n * 16;
          float v = acc[m][n][r];
          if (EPI == 6) v += a1 * v2[col] + a3 * v4[b512 + col];
          Cb[(int64_t)row * N + col] = f2bf(v);
        }
      }
    }
  }
}

// ---- f32 row -> bf16 row + row-sum (x only).  One block per row. ----
__global__ void cvt_row(const float* __restrict__ in, u16* __restrict__ out,
                        float* __restrict__ rowsum) {
  const int64_t row = blockIdx.x;
  const float4* ib = (const float4*)(in + row * 1152);
  U16x4* ob = (U16x4*)(out + row * 1152);
  float s = 0.f;
  for (int i = threadIdx.x; i < 288; i += 256) {
    float4 v = ib[i];
    s += v.x + v.y + v.z + v.w;
    U16x4 o = {f2bf(v.x), f2bf(v.y), f2bf(v.z), f2bf(v.w)};
    ob[i] = o;
  }
  s = wave_red(s);
  __shared__ float red[4];
  if ((threadIdx.x & 63) == 0) red[threadIdx.x >> 6] = s;
  __syncthreads();
  if (threadIdx.x == 0) rowsum[row] = red[0] + red[1] + red[2] + red[3];
}

// ---- x_h: f32 [C][N] -> bf16 [C][N] + bf16 [N][C] + partial rowsums ----
__global__ void prep_xh(const float* __restrict__ xh, u16* __restrict__ xhB,
                        u16* __restrict__ xhT, float* __restrict__ rxh_part) {
  __shared__ float tl[32][33];
  const int b = blockIdx.z;
  const int n0 = blockIdx.x * 32, c0 = blockIdx.y * 32;
  const float* ib = xh + (int64_t)b * 589824;
  const int tr = threadIdx.x >> 3, tc = (threadIdx.x & 7) * 4;
  const float4 v = *(const float4*)&ib[(int64_t)(c0 + tr) * 1152 + n0 + tc];
  tl[tr][tc] = v.x; tl[tr][tc + 1] = v.y; tl[tr][tc + 2] = v.z; tl[tr][tc + 3] = v.w;
  U16x4 o = {f2bf(v.x), f2bf(v.y), f2bf(v.z), f2bf(v.w)};
  *(U16x4*)&xhB[(int64_t)b * 589824 + (int64_t)(c0 + tr) * 1152 + n0 + tc] = o;
  __syncthreads();
  U16x4 ot = {f2bf(tl[tc][tr]), f2bf(tl[tc + 1][tr]),
              f2bf(tl[tc + 2][tr]), f2bf(tl[tc + 3][tr])};
  *(U16x4*)&xhT[(int64_t)b * 589824 + (int64_t)(n0 + tr) * 512 + c0 + tc] = ot;
  if (threadIdx.x < 32) {
    float s = 0;
#pragma unroll
    for (int c = 0; c < 32; ++c) s += tl[threadIdx.x][c];
    rxh_part[(n0 >> 5) * 16384 + b * 512 + c0 + threadIdx.x] = s;
  }
}

// ---- 4x fused 512x512 f32 -> bf16 transpose (blockIdx.z selects weight) ----
__global__ void transpose_cvt4(const float* __restrict__ s0, const float* __restrict__ s1,
                               const float* __restrict__ s2, const float* __restrict__ s3,
                               u16* __restrict__ d0, u16* __restrict__ d1,
                               u16* __restrict__ d2, u16* __restrict__ d3) {
  const int z = blockIdx.z;
  const float* in = z == 0 ? s0 : z == 1 ? s1 : z == 2 ? s2 : s3;
  u16* out = z == 0 ? d0 : z == 1 ? d1 : z == 2 ? d2 : d3;
  __shared__ float t[32][33];
  const int n0 = blockIdx.x * 32, c0 = blockIdx.y * 32;
  const int tr = threadIdx.x >> 3, tc = (threadIdx.x & 7) * 4;
  const float4 v = *(const float4*)&in[(int64_t)(c0 + tr) * 512 + n0 + tc];
  t[tr][tc] = v.x; t[tr][tc + 1] = v.y; t[tr][tc + 2] = v.z; t[tr][tc + 3] = v.w;
  __syncthreads();
  U16x4 o;
  o.x = f2bf(t[tc][tr]); o.y = f2bf(t[tc + 1][tr]);
  o.z = f2bf(t[tc + 2][tr]); o.w = f2bf(t[tc + 3][tr]);
  *(U16x4*)&out[(int64_t)(n0 + tr) * 512 + c0 + tc] = o;
}

// ---- f32 -> bf16 elementwise ----
__global__ void cvt_kernel(const float* __restrict__ in, u16* __restrict__ out, int n4) {
  const int i = blockIdx.x * 256 + threadIdx.x;
  if (i < n4) {
    const float4 v = ((const float4*)in)[i];
    U16x4 o = {f2bf(v.x), f2bf(v.y), f2bf(v.z), f2bf(v.w)};
    ((U16x4*)out)[i] = o;
  }
}

// ---- micro: rxh reduce (blocks 0..63) + BN prep + s2 (block 64) ----
__global__ void k_misc(const float* __restrict__ rxh_part, float* __restrict__ rxh,
                       const float* __restrict__ gamma, const float* __restrict__ beta,
                       const float* __restrict__ mean, const float* __restrict__ var,
                       const float* __restrict__ bw,
                       const float* __restrict__ bp, const float* __restrict__ bg,
                       float* __restrict__ sc2, float* __restrict__ shift0,
                       float* __restrict__ s2) {
  if (blockIdx.x < 64) {
    const int i = blockIdx.x * 256 + threadIdx.x;   // i = b*512 + c
    float s = 0;
#pragma unroll 4
    for (int p = 0; p < 36; ++p) s += rxh_part[p * 16384 + i];
    rxh[i] = s;
  } else {
    for (int c = threadIdx.x; c < 512; c += 256) {
      const float sc = gamma[c] * rsqrtf(var[c] + 1e-5f);
      sc2[c] = sc * (1.0f / 512.0f);
      shift0[c] = (bw[c] - mean[c]) * sc + beta[c];
    }
    if (threadIdx.x < 64) {
      float p = 0;
      for (int k = threadIdx.x; k < 512; k += 64) p += bp[k] * bg[k];
      p = wave_red(p);
      if (threadIdx.x == 0) s2[0] = p;
    }
  }
}

// ---- wave-per-row matvecs, stage 1: sigphi, tau2, h1, w1, c2 ----
// grid 8576 x 256 (34304 waves)
__global__ void k_mv1(const float* __restrict__ Wp, const float* __restrict__ Wt,
                      const float* __restrict__ Ww,
                      const u16* __restrict__ WpT, const u16* __restrict__ WgT,
                      const float* __restrict__ bg, const float* __restrict__ bt,
                      const float* __restrict__ bp,
                      const float* __restrict__ rx, const float* __restrict__ rxh,
                      float* __restrict__ sigphi, float* __restrict__ tau2,
                      float* __restrict__ h1, float* __restrict__ w1,
                      float* __restrict__ c2) {
  const int wid = blockIdx.x * 4 + (threadIdx.x >> 6);
  const int lane = threadIdx.x & 63;
  float dot = 0;
  if (wid < 16384) {                     // sigphi[b,t] = Wp[t,:].rxh[b,:]
    const int b = wid >> 9, t = wid & 511;
    const float* wr = Wp + (int64_t)t * 512;
    const float* vr = rxh + b * 512;
#pragma unroll
    for (int k = 0; k < 8; ++k) dot += wr[lane + k * 64] * vr[lane + k * 64];
    dot = wave_red(dot);
    if (lane == 0) sigphi[wid] = dot;
  } else if (wid < 32768) {              // tau2[b,t] = Wt[t,:].rx[b,:] + 1152 bt[t]
    const int r = wid - 16384, b = r >> 9, t = r & 511;
    const float* wr = Wt + (int64_t)t * 512;
    const float* vr = rx + b * 512;
#pragma unroll
    for (int k = 0; k < 8; ++k) dot += wr[lane + k * 64] * vr[lane + k * 64];
    dot = wave_red(dot);
    if (lane == 0) tau2[r] = dot + 1152.0f * bt[t];
  } else if (wid < 33280) {              // h1[j] = WpT[j,:].bg
    const int j = wid - 32768;
    const u16* wr = WpT + (int64_t)j * 512;
#pragma unroll
    for (int k = 0; k < 8; ++k) dot += bf2f(wr[lane + k * 64]) * bg[lane + k * 64];
    dot = wave_red(dot);
    if (lane == 0) h1[j] = dot;
  } else if (wid < 33792) {              // w1[c] = Ww[c,:].bt
    const int c = wid - 33280;
    const float* wr = Ww + (int64_t)c * 512;
#pragma unroll
    for (int k = 0; k < 8; ++k) dot += wr[lane + k * 64] * bt[lane + k * 64];
    dot = wave_red(dot);
    if (lane == 0) w1[c] = dot;
  } else {                               // c2[e] = WgT[e,:].bp
    const int e = wid - 33792;
    const u16* wr = WgT + (int64_t)e * 512;
#pragma unroll
    for (int k = 0; k < 8; ++k) dot += bf2f(wr[lane + k * 64]) * bp[lane + k * 64];
    dot = wave_red(dot);
    if (lane == 0) c2[e] = dot;
  }
}

// ---- wave-per-row matvecs, stage 2: c1, w2, s1 ----  grid 8200 x 256
__global__ void k_mv2(const u16* __restrict__ WgT, const float* __restrict__ Ww,
                      const float* __restrict__ bg,
                      const float* __restrict__ sigphi, const float* __restrict__ tau2,
                      float* __restrict__ c1, float* __restrict__ w2,
                      float* __restrict__ s1) {
  const int wid = blockIdx.x * 4 + (threadIdx.x >> 6);
  const int lane = threadIdx.x & 63;
  float dot = 0;
  if (wid < 16384) {                     // c1[b,t] = WgT[t,:].sigphi[b,:]
    const int b = wid >> 9, t = wid & 511;
    const u16* wr = WgT + (int64_t)t * 512;
    const float* vr = sigphi + b * 512;
#pragma unroll
    for (int k = 0; k < 8; ++k) dot += bf2f(wr[lane + k * 64]) * vr[lane + k * 64];
    dot = wave_red(dot);
    if (lane == 0) c1[wid] = dot;
  } else if (wid < 32768) {              // w2[b,t] = Ww[t,:].tau2[b,:]
    const int r = wid - 16384, b = r >> 9, t = r & 511;
    const float* wr = Ww + (int64_t)t * 512;
    const float* vr = tau2 + b * 512;
#pragma unroll
    for (int k = 0; k < 8; ++k) dot += wr[lane + k * 64] * vr[lane + k * 64];
    dot = wave_red(dot);
    if (lane == 0) w2[r] = dot;
  } else if (wid < 32800) {              // s1[b] = sigphi[b,:].bg
    const int b = wid - 32768;
    const float* vr = sigphi + b * 512;
#pragma unroll
    for (int k = 0; k < 8; ++k) dot += vr[lane + k * 64] * bg[lane + k * 64];
    dot = wave_red(dot);
    if (lane == 0) s1[b] = dot;
  }
}

// ---- shiftv[b,c] = sc2[c]*(R[b][c,:].h1 + s1[b]w1[c] + s2*w2[b,c]) + shift0[c]
// grid 4096 x 256 (wave per (b,c) row of R)
__global__ void k_shiftv(const u16* __restrict__ R, const float* __restrict__ h1,
                         const float* __restrict__ w1, const float* __restrict__ w2,
                         const float* __restrict__ s1, const float* __restrict__ s2,
                         const float* __restrict__ sc2, const float* __restrict__ shift0,
                         float* __restrict__ shiftv) {
  const int wid = blockIdx.x * 4 + (threadIdx.x >> 6);
  const int lane = threadIdx.x & 63;
  const int b = wid >> 9, c = wid & 511;
  const u16* rr = R + (int64_t)b * 262144 + (int64_t)c * 512;
  float dot = 0;
#pragma unroll
  for (int k = 0; k < 8; ++k) dot += bf2f(rr[lane + k * 64]) * h1[lane + k * 64];
  dot = wave_red(dot);
  if (lane == 0)
    shiftv[wid] = sc2[c] * (dot + s1[b] * w1[c] + s2[0] * w2[wid]) + shift0[c];
}

extern "C" void kernel_launch(void* const* d_in, const int* in_sizes, int n_in,
                              void* d_out, int out_size, void* d_ws, size_t ws_size,
                              hipStream_t stream) {
  const float* x     = (const float*)d_in[0];
  const float* x_h   = (const float*)d_in[1];
  const float* Wg    = (const float*)d_in[2];
  const float* bg    = (const float*)d_in[3];
  const float* Wt    = (const float*)d_in[4];
  const float* bt    = (const float*)d_in[5];
  const float* Wp    = (const float*)d_in[6];
  const float* bp    = (const float*)d_in[7];
  const float* Ww    = (const float*)d_in[8];
  const float* bw    = (const float*)d_in[9];
  const float* gamma = (const float*)d_in[10];
  const float* beta  = (const float*)d_in[11];
  const float* rmean = (const float*)d_in[12];
  const float* rvar  = (const float*)d_in[13];
  float* out = (float*)d_out;

  const int Bsz = 32, D = 512, N = 1152;
  const int64_t DN = (int64_t)D * N;   // 589824
  const int64_t DD = (int64_t)D * D;   // 262144

  char* ws = (char*)d_ws;
  const size_t KB = 1024, MB = 1048576;
  u16* WtT  = (u16*)(ws + 0);            // pair B: [WtT, WpT]
  u16* WpT  = (u16*)(ws + 512 * KB);
  u16* WwB  = (u16*)(ws + 1 * MB);       // pair A: [WwB, WgT]
  u16* WgT  = (u16*)(ws + 1 * MB + 512 * KB);
  u16* WaB  = (u16*)(ws + 2 * MB);       // pair C: [Wa, WbT]
  u16* WbTB = (u16*)(ws + 2 * MB + 512 * KB);
  u16* WwT  = (u16*)(ws + 3 * MB);
  float* rx     = (float*)(ws + 3 * MB + 512 * KB);
  float* rxh    = (float*)(ws + 3 * MB + 576 * KB);
  float* sigphi = (float*)(ws + 3 * MB + 640 * KB);
  float* tau2   = (float*)(ws + 3 * MB + 704 * KB);
  float* c1     = (float*)(ws + 3 * MB + 768 * KB);
  float* w2     = (float*)(ws + 3 * MB + 832 * KB);
  float* shiftv = (float*)(ws + 3 * MB + 896 * KB);
  float* h1     = (float*)(ws + 3 * MB + 960 * KB);
  float* w1     = (float*)(ws + 3 * MB + 962 * KB);
  float* c2     = (float*)(ws + 3 * MB + 964 * KB);
  float* sc2    = (float*)(ws + 3 * MB + 968 * KB);
  float* shift0 = (float*)(ws + 3 * MB + 970 * KB);
  float* s1     = (float*)(ws + 3 * MB + 972 * KB);
  float* s2     = (float*)(ws + 3 * MB + 974 * KB);
  u16* xB  = (u16*)(ws + 4 * MB);                  // 36 MB
  u16* xhB = (u16*)(ws + 40 * MB);                 // 36 MB
  u16* xhT = (u16*)(ws + 76 * MB);                 // 36 MB
  u16* SD1 = (u16*)(ws + 112 * MB);                // 17 MB (MT -> Q)
  u16* SD2 = (u16*)(ws + 130 * MB);                // 17 MB (R)
  float* rxh_part = (float*)(ws + 148 * MB);       // 2.25 MB

  // --- prep ---
  cvt_row<<<dim3(Bsz * D), 256, 0, stream>>>(x, xB, rx);
  prep_xh<<<dim3(36, 16, Bsz), 256, 0, stream>>>(x_h, xhB, xhT, rxh_part);
  transpose_cvt4<<<dim3(16, 16, 4), 256, 0, stream>>>(Wt, Wp, Wg, Ww, WtT, WpT, WgT, WwT);
  cvt_kernel<<<dim3(D * D / 4 / 256), 256, 0, stream>>>(Ww, WwB, D * D / 4);
  k_misc<<<dim3(65), 256, 0, stream>>>(rxh_part, rxh, gamma, beta, rmean, rvar, bw,
                                       bp, bg, sc2, shift0, s2);
  k_mv1<<<dim3(8576), 256, 0, stream>>>(Wp, Wt, Ww, WpT, WgT, bg, bt, bp, rx, rxh,
                                        sigphi, tau2, h1, w1, c2);
  k_mv2<<<dim3(8200), 256, 0, stream>>>(WgT, Ww, bg, sigphi, tau2, c1, w2, s1);
  // Wa = Ww*Wt (b=0) ; WbT[e,j] = sum_k Wg[k,e]Wp[k,j] (b=1) — one dispatch
  gemm_abt<0><<<dim3(4, 4, 2), 512, 0, stream>>>(
      WwB, DD, WtT, DD, WaB, DD, D, D, D, nullptr, nullptr, nullptr, nullptr, nullptr);

  // --- main chain (flat grids, XCD-batch swizzled) ---
  // G1: MT[j,i] = sum_n x_h[j,n] x[i,n]
  gemm_abt<0><<<dim3(16 * Bsz), 512, 0, stream>>>(
      xhB, DN, xB, DN, SD1, DD, D, D, N, nullptr, nullptr, nullptr, nullptr, nullptr);
  // G2: R[p,j] = sum_i Wa[p,i] MT[j,i]
  gemm_abt<0><<<dim3(16 * Bsz), 512, 0, stream>>>(
      WaB, 0, SD1, DD, SD2, DD, D, D, D, nullptr, nullptr, nullptr, nullptr, nullptr);
  // shiftv = sc2*(R.h1 + s1*w1 + s2*w2) + shift0  (replaces 58us k_uv)
  k_shiftv<<<dim3(4096), 256, 0, stream>>>(SD2, h1, w1, w2, s1, s2, sc2, shift0, shiftv);
  // G3: Q[p,e] = sum_j R[p,j] WbT[e,j] + rank-2 bias correction
  gemm_abt<6><<<dim3(16 * Bsz), 512, 0, stream>>>(
      SD2, DD, WbTB, 0, SD1, DD, D, D, D, w2, c2, w1, c1, nullptr);
  // G6: out[c,n] = sc2[c]*sum_e Q[c,e] xhT[n,e] + shiftv[b,c] + x[b,c,n]
  gemm_abt<4><<<dim3(36 * Bsz), 512, 0, stream>>>(
      SD1, DD, xhT, DN, out, DN, D, N, D, sc2, shiftv, nullptr, nullptr, x);
}